// Round 2
// baseline (1402.241 us; speedup 1.0000x reference)
//
#include <hip/hip_runtime.h>
#include <hip/hip_bf16.h>

#define B_  2
#define T_  2048
#define D_  1024
#define H_  16
#define HD_ 64

typedef __bf16 bf16x8 __attribute__((ext_vector_type(8)));
typedef float  f32x4  __attribute__((ext_vector_type(4)));

__device__ __forceinline__ __bf16 f2b(float f) {
  __hip_bfloat16 h = __float2bfloat16(f);
  return *reinterpret_cast<__bf16*>(&h);
}

__device__ __forceinline__ float wave_max(float v) {
#pragma unroll
  for (int o = 32; o > 0; o >>= 1) v = fmaxf(v, __shfl_xor(v, o, 64));
  return v;
}
__device__ __forceinline__ float wave_sum(float v) {
#pragma unroll
  for (int o = 32; o > 0; o >>= 1) v += __shfl_xor(v, o, 64);
  return v;
}

// ---------------------------------------------------------------------------
// Transpose + downcast: out_bf16[n][k] = in_f32[k][n]   (1024x1024)
// ---------------------------------------------------------------------------
__global__ __launch_bounds__(256) void transpose_k(const float* __restrict__ in,
                                                   __hip_bfloat16* __restrict__ out) {
  __shared__ float tile[64][65];  // +1 pad: read stride 65 -> conflict-free
  const int tx = threadIdx.x & 63, ty = threadIdx.x >> 6;
  const int bx = blockIdx.x * 64, by = blockIdx.y * 64;
#pragma unroll
  for (int i = ty; i < 64; i += 4)
    tile[i][tx] = in[(size_t)(by + i) * D_ + bx + tx];
  __syncthreads();
#pragma unroll
  for (int i = ty; i < 64; i += 4)
    out[(size_t)(bx + i) * D_ + by + tx] = __float2bfloat16(tile[tx][i]);
}

// ---------------------------------------------------------------------------
// Projection GEMM: C = A_f32[4096][1024] @ Bt_bf16[1024][1024]^T, out bf16,
// written permuted into (B,H,T,HD): ((b*H+h)*T+t)*64+d.
// Block 256 thr = 4 waves; tile 64(M)x64(N); wave tile 16x64.
// MFMA 16x16x32 bf16 layouts (verified):
//   A-frag: A[m=lane&15][k0+8*(lane>>4)+j]   B-frag: B[k...][n=lane&15]=Bt[n][k...]
//   D: row=4*(lane>>4)+r, col=lane&15
// ---------------------------------------------------------------------------
__global__ __launch_bounds__(256) void gemm_proj_k(const float* __restrict__ A,
                                                   const __hip_bfloat16* __restrict__ Bt,
                                                   __hip_bfloat16* __restrict__ C) {
  const int bm   = blockIdx.x * 64;
  const int bn   = blockIdx.y * 64;
  const int wave = threadIdx.x >> 6;
  const int lane = threadIdx.x & 63;
  const int lo   = lane & 15, q = lane >> 4;

  const float*          Arow  = A  + (size_t)(bm + wave * 16 + lo) * D_ + q * 8;
  const __hip_bfloat16* Bbase = Bt + (size_t)(bn + lo) * D_ + q * 8;

  f32x4 acc[4] = {{0.f,0.f,0.f,0.f},{0.f,0.f,0.f,0.f},{0.f,0.f,0.f,0.f},{0.f,0.f,0.f,0.f}};

  for (int k0 = 0; k0 < D_; k0 += 32) {
    f32x4 a0 = *(const f32x4*)(Arow + k0);
    f32x4 a1 = *(const f32x4*)(Arow + k0 + 4);
    bf16x8 a;
#pragma unroll
    for (int j = 0; j < 4; ++j) { a[j] = f2b(a0[j]); a[4 + j] = f2b(a1[j]); }
#pragma unroll
    for (int nt = 0; nt < 4; ++nt) {
      bf16x8 b = *(const bf16x8*)(Bbase + (size_t)nt * 16 * D_ + k0);
      acc[nt] = __builtin_amdgcn_mfma_f32_16x16x32_bf16(a, b, acc[nt], 0, 0, 0);
    }
  }

#pragma unroll
  for (int nt = 0; nt < 4; ++nt) {
#pragma unroll
    for (int r = 0; r < 4; ++r) {
      const int m = bm + wave * 16 + q * 4 + r;
      const int n = bn + nt * 16 + lo;
      const int b = m >> 11, t = m & (T_ - 1);
      const int h = n >> 6,  d = n & 63;
      C[(((size_t)(b * H_ + h) * T_ + t) << 6) + d] = __float2bfloat16(acc[nt][r]);
    }
  }
}

// ---------------------------------------------------------------------------
// Output GEMM: C_f32 = A_bf16[4096][1024] @ Bt_bf16[1024][1024]^T (plain write)
// ---------------------------------------------------------------------------
__global__ __launch_bounds__(256) void gemm_out_k(const __hip_bfloat16* __restrict__ A,
                                                  const __hip_bfloat16* __restrict__ Bt,
                                                  float* __restrict__ C) {
  const int bm   = blockIdx.x * 64;
  const int bn   = blockIdx.y * 64;
  const int wave = threadIdx.x >> 6;
  const int lane = threadIdx.x & 63;
  const int lo   = lane & 15, q = lane >> 4;

  const __hip_bfloat16* Arow  = A  + (size_t)(bm + wave * 16 + lo) * D_ + q * 8;
  const __hip_bfloat16* Bbase = Bt + (size_t)(bn + lo) * D_ + q * 8;

  f32x4 acc[4] = {{0.f,0.f,0.f,0.f},{0.f,0.f,0.f,0.f},{0.f,0.f,0.f,0.f},{0.f,0.f,0.f,0.f}};

  for (int k0 = 0; k0 < D_; k0 += 32) {
    bf16x8 a = *(const bf16x8*)(Arow + k0);
#pragma unroll
    for (int nt = 0; nt < 4; ++nt) {
      bf16x8 b = *(const bf16x8*)(Bbase + (size_t)nt * 16 * D_ + k0);
      acc[nt] = __builtin_amdgcn_mfma_f32_16x16x32_bf16(a, b, acc[nt], 0, 0, 0);
    }
  }

#pragma unroll
  for (int nt = 0; nt < 4; ++nt) {
#pragma unroll
    for (int r = 0; r < 4; ++r) {
      const int m = bm + wave * 16 + q * 4 + r;
      const int n = bn + nt * 16 + lo;
      C[(size_t)m * D_ + n] = acc[nt][r];
    }
  }
}

// ---------------------------------------------------------------------------
// Causal flash attention, vector-ALU. Q,K,V (B,H,T,HD) bf16 -> O (B,T,H,HD) bf16.
// 4 waves = 4 consecutive q-rows of one (b,h); wave-per-row online softmax.
// ---------------------------------------------------------------------------
__global__ __launch_bounds__(256) void attn_k(const __hip_bfloat16* __restrict__ Q,
                                              const __hip_bfloat16* __restrict__ K,
                                              const __hip_bfloat16* __restrict__ V,
                                              __hip_bfloat16* __restrict__ O) {
  __shared__ float Kt[64][66];
  __shared__ float qrow[4][64];
  __shared__ float pbuf[4][64];

  const int bh   = blockIdx.x;       // b*H + h
  const int t0   = blockIdx.y * 4;
  const int wave = threadIdx.x >> 6, lane = threadIdx.x & 63;
  const int t    = t0 + wave;

  const __hip_bfloat16* Kb = K + (size_t)bh * T_ * HD_;
  const __hip_bfloat16* Vb = V + (size_t)bh * T_ * HD_;

  qrow[wave][lane] = __bfloat162float(Q[((size_t)bh * T_ + t) * HD_ + lane]) * 0.125f;

  float m_run = -1e30f, l_run = 0.f, o_acc = 0.f;
  const int ntiles = (t0 + 3) / 64 + 1;  // uniform across block => barriers legal

  for (int tile = 0; tile < ntiles; ++tile) {
    const int jb = tile * 64;
    __syncthreads();
#pragma unroll
    for (int p = 0; p < 16; ++p) {
      const int e = threadIdx.x + p * 256;
      Kt[e >> 6][e & 63] = __bfloat162float(Kb[(size_t)jb * HD_ + e]);
    }
    __syncthreads();

    float s = -1e30f;
    if (jb + lane <= t) {
      float a = 0.f;
#pragma unroll
      for (int d = 0; d < 64; ++d) a += qrow[wave][d] * Kt[lane][d];
      s = a;
    }
    const float mt    = wave_max(s);
    const float m_new = fmaxf(m_run, mt);
    const float alpha = __expf(m_run - m_new);
    const float p_    = __expf(s - m_new);
    l_run = l_run * alpha + wave_sum(p_);
    pbuf[wave][lane] = p_;
    __syncthreads();

    o_acc *= alpha;
#pragma unroll
    for (int j = 0; j < 64; ++j)
      o_acc += pbuf[wave][j] * __bfloat162float(Vb[((size_t)jb + j) * HD_ + lane]);
    m_run = m_new;
  }

  const int b = bh >> 4, h = bh & 15;
  O[(((size_t)(b * T_ + t) * H_ + h) << 6) + lane] = __float2bfloat16(o_acc / l_run);
}

// ---------------------------------------------------------------------------
extern "C" void kernel_launch(void* const* d_in, const int* in_sizes, int n_in,
                              void* d_out, int out_size, void* d_ws, size_t ws_size,
                              hipStream_t stream) {
  const float* Xq  = (const float*)d_in[0];
  const float* Xkv = (const float*)d_in[1];
  // d_in[2] = causal mask (constant tril) — hardcoded in attn_k
  const float* Wq  = (const float*)d_in[3];
  const float* Wk  = (const float*)d_in[4];
  const float* Wv  = (const float*)d_in[5];
  const float* Wo  = (const float*)d_in[6];

  char* ws = (char*)d_ws;
  const size_t MB = 1024ull * 1024ull;
  __hip_bfloat16* WqT = (__hip_bfloat16*)(ws + 0  * MB);  // 2 MB each, bf16
  __hip_bfloat16* WkT = (__hip_bfloat16*)(ws + 2  * MB);
  __hip_bfloat16* WvT = (__hip_bfloat16*)(ws + 4  * MB);
  __hip_bfloat16* WoT = (__hip_bfloat16*)(ws + 6  * MB);
  __hip_bfloat16* Qw  = (__hip_bfloat16*)(ws + 8  * MB);  // (B,H,T,HD) bf16, 8 MB
  __hip_bfloat16* Kw  = (__hip_bfloat16*)(ws + 16 * MB);
  __hip_bfloat16* Vw  = (__hip_bfloat16*)(ws + 24 * MB);
  __hip_bfloat16* AO  = (__hip_bfloat16*)(ws + 32 * MB);  // (B,T,H,HD) bf16, 8 MB

  const dim3 tb(256);
  const dim3 tg(16, 16);
  transpose_k<<<tg, tb, 0, stream>>>(Wq, WqT);
  transpose_k<<<tg, tb, 0, stream>>>(Wk, WkT);
  transpose_k<<<tg, tb, 0, stream>>>(Wv, WvT);
  transpose_k<<<tg, tb, 0, stream>>>(Wo, WoT);

  const dim3 gg(64, 16);  // 4096/64 x 1024/64
  gemm_proj_k<<<gg, tb, 0, stream>>>(Xq,  WqT, Qw);
  gemm_proj_k<<<gg, tb, 0, stream>>>(Xkv, WkT, Kw);
  gemm_proj_k<<<gg, tb, 0, stream>>>(Xkv, WvT, Vw);

  attn_k<<<dim3(B_ * H_, T_ / 4), tb, 0, stream>>>(Qw, Kw, Vw, AO);

  gemm_out_k<<<gg, tb, 0, stream>>>(AO, WoT, (float*)d_out);
}

// Round 3
// 599.523 us; speedup vs baseline: 2.3389x; 2.3389x over previous
//
#include <hip/hip_runtime.h>
#include <hip/hip_bf16.h>

#define B_  2
#define T_  2048
#define D_  1024
#define H_  16
#define HD_ 64

typedef __bf16 bf16x8 __attribute__((ext_vector_type(8)));
typedef float  f32x4  __attribute__((ext_vector_type(4)));

__device__ __forceinline__ __bf16 f2b(float f) {
  __hip_bfloat16 h = __float2bfloat16(f);
  return *reinterpret_cast<__bf16*>(&h);
}

// ---------------------------------------------------------------------------
// Transpose + downcast: out_bf16[n][k] = in_f32[k][n]   (1024x1024)
// ---------------------------------------------------------------------------
__global__ __launch_bounds__(256) void transpose_k(const float* __restrict__ in,
                                                   __hip_bfloat16* __restrict__ out) {
  __shared__ float tile[64][65];
  const int tx = threadIdx.x & 63, ty = threadIdx.x >> 6;
  const int bx = blockIdx.x * 64, by = blockIdx.y * 64;
#pragma unroll
  for (int i = ty; i < 64; i += 4)
    tile[i][tx] = in[(size_t)(by + i) * D_ + bx + tx];
  __syncthreads();
#pragma unroll
  for (int i = ty; i < 64; i += 4)
    out[(size_t)(bx + i) * D_ + by + tx] = __float2bfloat16(tile[tx][i]);
}

// ---------------------------------------------------------------------------
// Projection GEMM: C = A_f32[4096][1024] @ Bt_bf16[1024][1024]^T, out bf16.
// scale folded into epilogue (Q: 0.125). vmode=0 -> (B,H,T,HD); vmode=1 ->
// V transposed (B,H,HD,T) so attention PV B-frags are contiguous.
// ---------------------------------------------------------------------------
__global__ __launch_bounds__(256) void gemm_proj_k(const float* __restrict__ A,
                                                   const __hip_bfloat16* __restrict__ Bt,
                                                   __hip_bfloat16* __restrict__ C,
                                                   float scale, int vmode) {
  const int bm   = blockIdx.x * 64;
  const int bn   = blockIdx.y * 64;
  const int wave = threadIdx.x >> 6;
  const int lane = threadIdx.x & 63;
  const int lo   = lane & 15, q = lane >> 4;

  const float*          Arow  = A  + (size_t)(bm + wave * 16 + lo) * D_ + q * 8;
  const __hip_bfloat16* Bbase = Bt + (size_t)(bn + lo) * D_ + q * 8;

  f32x4 acc[4] = {{0.f,0.f,0.f,0.f},{0.f,0.f,0.f,0.f},{0.f,0.f,0.f,0.f},{0.f,0.f,0.f,0.f}};

  for (int k0 = 0; k0 < D_; k0 += 32) {
    f32x4 a0 = *(const f32x4*)(Arow + k0);
    f32x4 a1 = *(const f32x4*)(Arow + k0 + 4);
    bf16x8 a;
#pragma unroll
    for (int j = 0; j < 4; ++j) { a[j] = f2b(a0[j]); a[4 + j] = f2b(a1[j]); }
#pragma unroll
    for (int nt = 0; nt < 4; ++nt) {
      bf16x8 b = *(const bf16x8*)(Bbase + (size_t)nt * 16 * D_ + k0);
      acc[nt] = __builtin_amdgcn_mfma_f32_16x16x32_bf16(a, b, acc[nt], 0, 0, 0);
    }
  }

#pragma unroll
  for (int nt = 0; nt < 4; ++nt) {
#pragma unroll
    for (int r = 0; r < 4; ++r) {
      const int m = bm + wave * 16 + q * 4 + r;
      const int n = bn + nt * 16 + lo;
      const int b = m >> 11, t = m & (T_ - 1);
      const int h = n >> 6,  d = n & 63;
      const __hip_bfloat16 val = __float2bfloat16(acc[nt][r] * scale);
      if (vmode == 0)
        C[(((size_t)(b * H_ + h) * T_ + t) << 6) + d] = val;                 // (B,H,T,HD)
      else
        C[((size_t)(b * H_ + h) * HD_ + d) * T_ + t] = val;                  // (B,H,HD,T)
    }
  }
}

// ---------------------------------------------------------------------------
// Output GEMM: C_f32 = A_bf16[4096][1024] @ Bt_bf16[1024][1024]^T
// ---------------------------------------------------------------------------
__global__ __launch_bounds__(256) void gemm_out_k(const __hip_bfloat16* __restrict__ A,
                                                  const __hip_bfloat16* __restrict__ Bt,
                                                  float* __restrict__ C) {
  const int bm   = blockIdx.x * 64;
  const int bn   = blockIdx.y * 64;
  const int wave = threadIdx.x >> 6;
  const int lane = threadIdx.x & 63;
  const int lo   = lane & 15, q = lane >> 4;

  const __hip_bfloat16* Arow  = A  + (size_t)(bm + wave * 16 + lo) * D_ + q * 8;
  const __hip_bfloat16* Bbase = Bt + (size_t)(bn + lo) * D_ + q * 8;

  f32x4 acc[4] = {{0.f,0.f,0.f,0.f},{0.f,0.f,0.f,0.f},{0.f,0.f,0.f,0.f},{0.f,0.f,0.f,0.f}};

  for (int k0 = 0; k0 < D_; k0 += 32) {
    bf16x8 a = *(const bf16x8*)(Arow + k0);
#pragma unroll
    for (int nt = 0; nt < 4; ++nt) {
      bf16x8 b = *(const bf16x8*)(Bbase + (size_t)nt * 16 * D_ + k0);
      acc[nt] = __builtin_amdgcn_mfma_f32_16x16x32_bf16(a, b, acc[nt], 0, 0, 0);
    }
  }

#pragma unroll
  for (int nt = 0; nt < 4; ++nt) {
#pragma unroll
    for (int r = 0; r < 4; ++r) {
      const int m = bm + wave * 16 + q * 4 + r;
      const int n = bn + nt * 16 + lo;
      C[(size_t)m * D_ + n] = acc[nt][r];
    }
  }
}

// ---------------------------------------------------------------------------
// MFMA causal flash attention.
// Q,K: (B,H,T,HD) bf16 (Q pre-scaled by 0.125). Vt: (B,H,HD,T) bf16.
// O: (B,T,H*HD) bf16. Block = 4 waves = 64 q-rows of one (b,h); K-tile = 64.
// Per wave: S-tile 16x64 via 8 MFMAs (A=Q, B=K, both contiguous-16B loads),
// online softmax in D-layout (row=4*qh+r, col=lane&15), P->LDS (wave-private,
// 72-elem padded rows), PV via 8 MFMAs (A=P from LDS, B=Vt contiguous).
// ---------------------------------------------------------------------------
__global__ __launch_bounds__(256) void attn_mfma_k(const __hip_bfloat16* __restrict__ Q,
                                                   const __hip_bfloat16* __restrict__ K,
                                                   const __hip_bfloat16* __restrict__ Vt,
                                                   __hip_bfloat16* __restrict__ O) {
  __shared__ __align__(16) __bf16 Pl[4][16][72];  // wave-private P tiles

  const int bh   = blockIdx.x;                  // b*H + h
  const int qb   = (int)gridDim.y - 1 - (int)blockIdx.y;  // longest blocks first
  const int t0   = qb * 64;
  const int wave = threadIdx.x >> 6, lane = threadIdx.x & 63;
  const int lo   = lane & 15, qh = lane >> 4;

  const __hip_bfloat16* Qb = Q  + (size_t)bh * T_ * HD_;
  const __hip_bfloat16* Kb = K  + (size_t)bh * T_ * HD_;
  const __hip_bfloat16* Vb = Vt + (size_t)bh * HD_ * T_;

  // Q fragments for this wave's 16 rows (reused across all K-tiles)
  bf16x8 qf[2];
  qf[0] = *(const bf16x8*)(Qb + (size_t)(t0 + wave * 16 + lo) * HD_ + qh * 8);
  qf[1] = *(const bf16x8*)(Qb + (size_t)(t0 + wave * 16 + lo) * HD_ + 32 + qh * 8);

  f32x4 o[4] = {{0.f,0.f,0.f,0.f},{0.f,0.f,0.f,0.f},{0.f,0.f,0.f,0.f},{0.f,0.f,0.f,0.f}};
  float mrun[4] = {-1e30f, -1e30f, -1e30f, -1e30f};
  float lrun[4] = {0.f, 0.f, 0.f, 0.f};

  for (int jb = 0; jb <= t0; jb += 64) {
    const bool diag = (jb == t0);

    // ---- S = Q K^T (16x64 per wave) ----
    f32x4 s[4];
#pragma unroll
    for (int nt = 0; nt < 4; ++nt) {
      if (diag && nt > wave) { s[nt] = (f32x4){-1e30f, -1e30f, -1e30f, -1e30f}; continue; }
      f32x4 acc = {0.f, 0.f, 0.f, 0.f};
#pragma unroll
      for (int ks = 0; ks < 2; ++ks) {
        bf16x8 kf = *(const bf16x8*)(Kb + (size_t)(jb + nt * 16 + lo) * HD_ + ks * 32 + qh * 8);
        acc = __builtin_amdgcn_mfma_f32_16x16x32_bf16(qf[ks], kf, acc, 0, 0, 0);
      }
      if (diag && nt == wave) {
#pragma unroll
        for (int r = 0; r < 4; ++r)
          if (lo > 4 * qh + r) acc[r] = -1e30f;   // key_local > q_local
      }
      s[nt] = acc;
    }

    // ---- online softmax (rows = 4*qh+r, cols spread over 16 lanes) ----
    float mr[4], alpha[4];
#pragma unroll
    for (int r = 0; r < 4; ++r) {
      mr[r] = fmaxf(fmaxf(s[0][r], s[1][r]), fmaxf(s[2][r], s[3][r]));
#pragma unroll
      for (int msk = 1; msk < 16; msk <<= 1)
        mr[r] = fmaxf(mr[r], __shfl_xor(mr[r], msk, 64));
      const float mn = fmaxf(mrun[r], mr[r]);
      alpha[r] = __expf(mrun[r] - mn);
      mrun[r] = mn;
    }

    __syncthreads();  // prior tile's P reads complete before overwrite

    float psum[4] = {0.f, 0.f, 0.f, 0.f};
#pragma unroll
    for (int nt = 0; nt < 4; ++nt)
#pragma unroll
      for (int r = 0; r < 4; ++r) {
        const float p = __expf(s[nt][r] - mrun[r]);
        psum[r] += p;
        Pl[wave][4 * qh + r][nt * 16 + lo] = f2b(p);
      }
#pragma unroll
    for (int r = 0; r < 4; ++r) {
#pragma unroll
      for (int msk = 1; msk < 16; msk <<= 1)
        psum[r] += __shfl_xor(psum[r], msk, 64);
      lrun[r] = lrun[r] * alpha[r] + psum[r];
    }
#pragma unroll
    for (int nt = 0; nt < 4; ++nt)
#pragma unroll
      for (int r = 0; r < 4; ++r) o[nt][r] *= alpha[r];

    __syncthreads();  // P visible

    // ---- O += P V (A-frag = P from LDS, B-frag = Vt contiguous) ----
#pragma unroll
    for (int ks = 0; ks < 2; ++ks) {
      bf16x8 pf = *(const bf16x8*)&Pl[wave][lo][ks * 32 + qh * 8];
#pragma unroll
      for (int nt = 0; nt < 4; ++nt) {
        bf16x8 vf = *(const bf16x8*)(Vb + (size_t)(nt * 16 + lo) * T_ + jb + ks * 32 + qh * 8);
        o[nt] = __builtin_amdgcn_mfma_f32_16x16x32_bf16(pf, vf, o[nt], 0, 0, 0);
      }
    }
  }

  // ---- epilogue: O/l -> (B,T,H*HD) bf16 ----
  const int b = bh >> 4, h = bh & 15;
#pragma unroll
  for (int nt = 0; nt < 4; ++nt)
#pragma unroll
    for (int r = 0; r < 4; ++r) {
      const int q = t0 + wave * 16 + 4 * qh + r;
      O[((size_t)(b * T_ + q) * H_ * HD_) + h * HD_ + nt * 16 + lo] =
          __float2bfloat16(o[nt][r] / lrun[r]);
    }
}

// ---------------------------------------------------------------------------
extern "C" void kernel_launch(void* const* d_in, const int* in_sizes, int n_in,
                              void* d_out, int out_size, void* d_ws, size_t ws_size,
                              hipStream_t stream) {
  const float* Xq  = (const float*)d_in[0];
  const float* Xkv = (const float*)d_in[1];
  // d_in[2] = causal mask (constant tril) — hardcoded
  const float* Wq  = (const float*)d_in[3];
  const float* Wk  = (const float*)d_in[4];
  const float* Wv  = (const float*)d_in[5];
  const float* Wo  = (const float*)d_in[6];

  char* ws = (char*)d_ws;
  const size_t MB = 1024ull * 1024ull;
  __hip_bfloat16* WqT = (__hip_bfloat16*)(ws + 0  * MB);
  __hip_bfloat16* WkT = (__hip_bfloat16*)(ws + 2  * MB);
  __hip_bfloat16* WvT = (__hip_bfloat16*)(ws + 4  * MB);
  __hip_bfloat16* WoT = (__hip_bfloat16*)(ws + 6  * MB);
  __hip_bfloat16* Qw  = (__hip_bfloat16*)(ws + 8  * MB);  // (B,H,T,HD)
  __hip_bfloat16* Kw  = (__hip_bfloat16*)(ws + 16 * MB);  // (B,H,T,HD)
  __hip_bfloat16* Vw  = (__hip_bfloat16*)(ws + 24 * MB);  // (B,H,HD,T) transposed
  __hip_bfloat16* AO  = (__hip_bfloat16*)(ws + 32 * MB);  // (B,T,H*HD)

  const dim3 tb(256);
  const dim3 tg(16, 16);
  transpose_k<<<tg, tb, 0, stream>>>(Wq, WqT);
  transpose_k<<<tg, tb, 0, stream>>>(Wk, WkT);
  transpose_k<<<tg, tb, 0, stream>>>(Wv, WvT);
  transpose_k<<<tg, tb, 0, stream>>>(Wo, WoT);

  const dim3 gg(64, 16);
  gemm_proj_k<<<gg, tb, 0, stream>>>(Xq,  WqT, Qw, 0.125f, 0);  // scale folded
  gemm_proj_k<<<gg, tb, 0, stream>>>(Xkv, WkT, Kw, 1.0f,   0);
  gemm_proj_k<<<gg, tb, 0, stream>>>(Xkv, WvT, Vw, 1.0f,   1);

  attn_mfma_k<<<dim3(B_ * H_, T_ / 64), tb, 0, stream>>>(Qw, Kw, Vw, AO);

  gemm_out_k<<<dim3(64, 16), tb, 0, stream>>>(AO, WoT, (float*)d_out);
}

// Round 4
// 389.464 us; speedup vs baseline: 3.6004x; 1.5394x over previous
//
#include <hip/hip_runtime.h>
#include <hip/hip_bf16.h>

#define B_  2
#define T_  2048
#define D_  1024
#define H_  16
#define HD_ 64

typedef __bf16 bf16x8 __attribute__((ext_vector_type(8)));
typedef float  f32x4  __attribute__((ext_vector_type(4)));

__device__ __forceinline__ __bf16 f2b(float f) {
  __hip_bfloat16 h = __float2bfloat16(f);
  return *reinterpret_cast<__bf16*>(&h);
}

// async global->LDS, 16B per lane. LDS dest must be wave-uniform base + lane*16.
__device__ __forceinline__ void gload_lds16(const __bf16* g, __bf16* l) {
  __builtin_amdgcn_global_load_lds((const unsigned int*)g, (unsigned int*)l, 16, 0, 0);
}

// ---------------------------------------------------------------------------
// fp32 -> bf16 bulk convert (4 elems/thread, 8B packed stores)
// ---------------------------------------------------------------------------
__global__ __launch_bounds__(256) void cvt_k(const float* __restrict__ x,
                                             __hip_bfloat16* __restrict__ y) {
  const size_t i = ((size_t)blockIdx.x * 256 + threadIdx.x) * 4;
  f32x4 v = *(const f32x4*)(x + i);
  union { ushort4 u; __hip_bfloat16 h[4]; } o;
#pragma unroll
  for (int j = 0; j < 4; ++j) o.h[j] = __float2bfloat16(v[j]);
  *(ushort4*)(y + i) = o.u;
}

// ---------------------------------------------------------------------------
// Weight transpose + downcast: out_bf16[n][k] = in_f32[k][n]   (1024x1024)
// ---------------------------------------------------------------------------
__global__ __launch_bounds__(256) void transpose_k(const float* __restrict__ in,
                                                   __hip_bfloat16* __restrict__ out) {
  __shared__ float tile[64][65];
  const int tx = threadIdx.x & 63, ty = threadIdx.x >> 6;
  const int bx = blockIdx.x * 64, by = blockIdx.y * 64;
#pragma unroll
  for (int i = ty; i < 64; i += 4)
    tile[i][tx] = in[(size_t)(by + i) * D_ + bx + tx];
  __syncthreads();
#pragma unroll
  for (int i = ty; i < 64; i += 4)
    out[(size_t)(bx + i) * D_ + by + tx] = __float2bfloat16(tile[tx][i]);
}

// ---------------------------------------------------------------------------
// V head-wise transpose: (B,H,T,HD) -> (B,H,HD,T), bf16, coalesced both sides
// ---------------------------------------------------------------------------
__global__ __launch_bounds__(256) void vtrans_k(const __hip_bfloat16* __restrict__ in,
                                                __hip_bfloat16* __restrict__ out) {
  __shared__ __hip_bfloat16 tl[64][65];
  const int bh = blockIdx.y;
  const int t0 = blockIdx.x * 64;
  const int tx = threadIdx.x & 63, ty = threadIdx.x >> 6;
  const __hip_bfloat16* src = in + (size_t)bh * T_ * HD_;
  __hip_bfloat16* dst = out + (size_t)bh * HD_ * T_;
#pragma unroll
  for (int i = ty; i < 64; i += 4)
    tl[i][tx] = src[(size_t)(t0 + i) * HD_ + tx];
  __syncthreads();
#pragma unroll
  for (int i = ty; i < 64; i += 4)
    dst[(size_t)i * T_ + t0 + tx] = tl[tx][i];
}

// ---------------------------------------------------------------------------
// 128x128-tile GEMM: C = A_bf16[4096][1024] @ Bt_bf16[1024][1024]^T
// BK=32, async global_load_lds staging (16B/lane), 4 waves 2x2, 4x4 MFMA/wave.
// mode 0: C f32 plain [4096][1024].
// mode 1: C bf16 * scale, permuted to (B,H,T,HD): ((b*H+h)*T+t)*64+d.
// ---------------------------------------------------------------------------
__global__ __launch_bounds__(256) void gemm128_k(const __bf16* __restrict__ A,
                                                 const __bf16* __restrict__ Bt,
                                                 void* __restrict__ Cv,
                                                 int mode, float scale) {
  __shared__ __align__(16) __bf16 Al[128 * 32];
  __shared__ __align__(16) __bf16 Bl[128 * 32];

  const int bm = blockIdx.x * 128;
  const int bn = blockIdx.y * 128;
  const int wave = threadIdx.x >> 6, lane = threadIdx.x & 63;
  const int wm = (wave >> 1) * 64, wn = (wave & 1) * 64;
  const int lo = lane & 15, qh = lane >> 4;

  // staging map: thread i owns LDS 16B chunk i -> row i/4, k-chunk (i%4)*8
  const int srow = threadIdx.x >> 2;
  const int skc  = (threadIdx.x & 3) * 8;
  const __bf16* Ag0 = A  + (size_t)(bm + srow) * D_ + skc;
  const __bf16* Bg0 = Bt + (size_t)(bn + srow) * D_ + skc;
  __bf16* Al0 = Al + threadIdx.x * 8;
  __bf16* Bl0 = Bl + threadIdx.x * 8;

  f32x4 acc[4][4] = {};

  for (int k0 = 0; k0 < D_; k0 += 32) {
    __syncthreads();  // previous tile's ds_reads done before overwrite
    gload_lds16(Ag0 + k0,            Al0);
    gload_lds16(Ag0 + 64 * D_ + k0,  Al0 + 64 * 32);
    gload_lds16(Bg0 + k0,            Bl0);
    gload_lds16(Bg0 + 64 * D_ + k0,  Bl0 + 64 * 32);
    __syncthreads();  // staged data visible (vmcnt drained by barrier)

    bf16x8 af[4], bfr[4];
#pragma unroll
    for (int mt = 0; mt < 4; ++mt)
      af[mt] = *(const bf16x8*)(Al + (wm + mt * 16 + lo) * 32 + qh * 8);
#pragma unroll
    for (int nt = 0; nt < 4; ++nt)
      bfr[nt] = *(const bf16x8*)(Bl + (wn + nt * 16 + lo) * 32 + qh * 8);
#pragma unroll
    for (int mt = 0; mt < 4; ++mt)
#pragma unroll
      for (int nt = 0; nt < 4; ++nt)
        acc[mt][nt] = __builtin_amdgcn_mfma_f32_16x16x32_bf16(af[mt], bfr[nt], acc[mt][nt], 0, 0, 0);
  }

  if (mode == 0) {
    float* C = (float*)Cv;
#pragma unroll
    for (int mt = 0; mt < 4; ++mt)
#pragma unroll
      for (int nt = 0; nt < 4; ++nt)
#pragma unroll
        for (int r = 0; r < 4; ++r) {
          const int m = bm + wm + mt * 16 + 4 * qh + r;
          const int n = bn + wn + nt * 16 + lo;
          C[(size_t)m * D_ + n] = acc[mt][nt][r];
        }
  } else {
    __hip_bfloat16* C = (__hip_bfloat16*)Cv;
#pragma unroll
    for (int mt = 0; mt < 4; ++mt)
#pragma unroll
      for (int nt = 0; nt < 4; ++nt)
#pragma unroll
        for (int r = 0; r < 4; ++r) {
          const int m = bm + wm + mt * 16 + 4 * qh + r;
          const int n = bn + wn + nt * 16 + lo;
          const int b = m >> 11, t = m & (T_ - 1);
          const int h = n >> 6,  d = n & 63;
          C[(((size_t)(b * H_ + h) * T_ + t) << 6) + d] =
              __float2bfloat16(acc[mt][nt][r] * scale);
        }
  }
}

// ---------------------------------------------------------------------------
// MFMA causal flash attention (no block barriers: P tile is wave-private).
// Q,K: (B,H,T,HD) bf16 (Q pre-scaled 0.125). Vt: (B,H,HD,T). O: (B,T,H*HD).
// ---------------------------------------------------------------------------
__global__ __launch_bounds__(256) void attn_mfma_k(const __hip_bfloat16* __restrict__ Q,
                                                   const __hip_bfloat16* __restrict__ K,
                                                   const __hip_bfloat16* __restrict__ Vt,
                                                   __hip_bfloat16* __restrict__ O) {
  __shared__ __align__(16) __bf16 Pl[4][16][72];  // wave-private P tiles

  const int bh   = blockIdx.x;
  const int qb   = (int)gridDim.y - 1 - (int)blockIdx.y;  // longest first
  const int t0   = qb * 64;
  const int wave = threadIdx.x >> 6, lane = threadIdx.x & 63;
  const int lo   = lane & 15, qh = lane >> 4;

  const __hip_bfloat16* Qb = Q  + (size_t)bh * T_ * HD_;
  const __hip_bfloat16* Kb = K  + (size_t)bh * T_ * HD_;
  const __hip_bfloat16* Vb = Vt + (size_t)bh * HD_ * T_;

  bf16x8 qf[2];
  qf[0] = *(const bf16x8*)(Qb + (size_t)(t0 + wave * 16 + lo) * HD_ + qh * 8);
  qf[1] = *(const bf16x8*)(Qb + (size_t)(t0 + wave * 16 + lo) * HD_ + 32 + qh * 8);

  f32x4 o[4] = {};
  float mrun[4] = {-1e30f, -1e30f, -1e30f, -1e30f};
  float lrun[4] = {0.f, 0.f, 0.f, 0.f};

  for (int jb = 0; jb <= t0; jb += 64) {
    const bool diag = (jb == t0);

    f32x4 s[4];
#pragma unroll
    for (int nt = 0; nt < 4; ++nt) {
      if (diag && nt > wave) { s[nt] = (f32x4){-1e30f, -1e30f, -1e30f, -1e30f}; continue; }
      f32x4 acc = {0.f, 0.f, 0.f, 0.f};
#pragma unroll
      for (int ks = 0; ks < 2; ++ks) {
        bf16x8 kf = *(const bf16x8*)(Kb + (size_t)(jb + nt * 16 + lo) * HD_ + ks * 32 + qh * 8);
        acc = __builtin_amdgcn_mfma_f32_16x16x32_bf16(qf[ks], kf, acc, 0, 0, 0);
      }
      if (diag && nt == wave) {
#pragma unroll
        for (int r = 0; r < 4; ++r)
          if (lo > 4 * qh + r) acc[r] = -1e30f;
      }
      s[nt] = acc;
    }

    float mr[4], alpha[4];
#pragma unroll
    for (int r = 0; r < 4; ++r) {
      mr[r] = fmaxf(fmaxf(s[0][r], s[1][r]), fmaxf(s[2][r], s[3][r]));
#pragma unroll
      for (int msk = 1; msk < 16; msk <<= 1)
        mr[r] = fmaxf(mr[r], __shfl_xor(mr[r], msk, 64));
      const float mn = fmaxf(mrun[r], mr[r]);
      alpha[r] = __expf(mrun[r] - mn);
      mrun[r] = mn;
    }

    float psum[4] = {0.f, 0.f, 0.f, 0.f};
#pragma unroll
    for (int nt = 0; nt < 4; ++nt)
#pragma unroll
      for (int r = 0; r < 4; ++r) {
        const float p = __expf(s[nt][r] - mrun[r]);
        psum[r] += p;
        Pl[wave][4 * qh + r][nt * 16 + lo] = f2b(p);
      }
#pragma unroll
    for (int r = 0; r < 4; ++r) {
#pragma unroll
      for (int msk = 1; msk < 16; msk <<= 1)
        psum[r] += __shfl_xor(psum[r], msk, 64);
      lrun[r] = lrun[r] * alpha[r] + psum[r];
    }
#pragma unroll
    for (int nt = 0; nt < 4; ++nt)
#pragma unroll
      for (int r = 0; r < 4; ++r) o[nt][r] *= alpha[r];

    // no __syncthreads(): Pl[wave] is wave-private; lgkmcnt orders ds ops
#pragma unroll
    for (int ks = 0; ks < 2; ++ks) {
      bf16x8 pf = *(const bf16x8*)&Pl[wave][lo][ks * 32 + qh * 8];
#pragma unroll
      for (int nt = 0; nt < 4; ++nt) {
        bf16x8 vf = *(const bf16x8*)(Vb + (size_t)(nt * 16 + lo) * T_ + jb + ks * 32 + qh * 8);
        o[nt] = __builtin_amdgcn_mfma_f32_16x16x32_bf16(pf, vf, o[nt], 0, 0, 0);
      }
    }
  }

  const int b = bh >> 4, h = bh & 15;
#pragma unroll
  for (int nt = 0; nt < 4; ++nt)
#pragma unroll
    for (int r = 0; r < 4; ++r) {
      const int q = t0 + wave * 16 + 4 * qh + r;
      O[((size_t)(b * T_ + q) * H_ * HD_) + h * HD_ + nt * 16 + lo] =
          __float2bfloat16(o[nt][r] / lrun[r]);
    }
}

// ---------------------------------------------------------------------------
extern "C" void kernel_launch(void* const* d_in, const int* in_sizes, int n_in,
                              void* d_out, int out_size, void* d_ws, size_t ws_size,
                              hipStream_t stream) {
  const float* Xq  = (const float*)d_in[0];
  const float* Xkv = (const float*)d_in[1];
  // d_in[2] = causal mask (constant tril) — hardcoded
  const float* Wq  = (const float*)d_in[3];
  const float* Wk  = (const float*)d_in[4];
  const float* Wv  = (const float*)d_in[5];
  const float* Wo  = (const float*)d_in[6];

  char* ws = (char*)d_ws;
  const size_t MB = 1024ull * 1024ull;
  __hip_bfloat16* WqT   = (__hip_bfloat16*)(ws + 0  * MB);
  __hip_bfloat16* WkT   = (__hip_bfloat16*)(ws + 2  * MB);
  __hip_bfloat16* WvT   = (__hip_bfloat16*)(ws + 4  * MB);
  __hip_bfloat16* WoT   = (__hip_bfloat16*)(ws + 6  * MB);
  __hip_bfloat16* Qw    = (__hip_bfloat16*)(ws + 8  * MB);  // (B,H,T,HD)
  __hip_bfloat16* Kw    = (__hip_bfloat16*)(ws + 16 * MB);  // (B,H,T,HD)
  __hip_bfloat16* Vw    = (__hip_bfloat16*)(ws + 24 * MB);  // (B,H,HD,T)
  __hip_bfloat16* AO    = (__hip_bfloat16*)(ws + 32 * MB);  // Vtmp, then attn out
  __hip_bfloat16* Xq_b  = (__hip_bfloat16*)(ws + 40 * MB);
  __hip_bfloat16* Xkv_b = (__hip_bfloat16*)(ws + 48 * MB);

  const dim3 tb(256);
  cvt_k<<<dim3(4096), tb, 0, stream>>>(Xq,  Xq_b);   // 4096*1024 elems
  cvt_k<<<dim3(4096), tb, 0, stream>>>(Xkv, Xkv_b);

  const dim3 tg(16, 16);
  transpose_k<<<tg, tb, 0, stream>>>(Wq, WqT);
  transpose_k<<<tg, tb, 0, stream>>>(Wk, WkT);
  transpose_k<<<tg, tb, 0, stream>>>(Wv, WvT);
  transpose_k<<<tg, tb, 0, stream>>>(Wo, WoT);

  const dim3 gg(32, 8);  // 4096/128 x 1024/128
  gemm128_k<<<gg, tb, 0, stream>>>((const __bf16*)Xq_b,  (const __bf16*)WqT, Qw, 1, 0.125f);
  gemm128_k<<<gg, tb, 0, stream>>>((const __bf16*)Xkv_b, (const __bf16*)WkT, Kw, 1, 1.0f);
  gemm128_k<<<gg, tb, 0, stream>>>((const __bf16*)Xkv_b, (const __bf16*)WvT, AO, 1, 1.0f);

  vtrans_k<<<dim3(32, 32), tb, 0, stream>>>(AO, Vw);  // (B,H,T,HD)->(B,H,HD,T)

  attn_mfma_k<<<dim3(B_ * H_, T_ / 64), tb, 0, stream>>>(Qw, Kw, Vw, AO);

  gemm128_k<<<gg, tb, 0, stream>>>((const __bf16*)AO, (const __bf16*)WoT, d_out, 0, 1.0f);
}